// Round 2
// baseline (128.315 us; speedup 1.0000x reference)
//
#include <hip/hip_runtime.h>

// Chamfer distance, pred/target: (4, 8192, 3) fp32.
// Fused both-directions pass: each d2(i,j) computed ONCE; updates the
// row-min (forward, thread-local registers) and the col-min (backward,
// LDS ds_min atomics with per-lane staggered j to avoid same-address
// serialization). Partial mins merged via global int atomicMin (valid
// since d2 >= 0 -> float order == int order).

#define NPTS   8192
#define BATCH  4
#define RPT    8                  // register-resident rows per thread
#define BLOCK  256
#define PTILE  (RPT * BLOCK)      // 2048 rows per block
#define NCHUNK 32
#define CHUNK  (NPTS / NCHUNK)    // 256 streamed cols per block

__global__ __launch_bounds__(BLOCK) void chamfer_pairs(
    const float* __restrict__ pred, const float* __restrict__ target,
    int* __restrict__ mins)
{
    __shared__ float qs[3][CHUNK];      // staged target chunk (SoA)
    __shared__ int   cmin_s[CHUNK];     // per-block column mins (int bits)

    const int b = blockIdx.z;
    const float* __restrict__ P = pred   + b * NPTS * 3;
    const float* __restrict__ Q = target + b * NPTS * 3;
    int* __restrict__ fwd = mins + b * NPTS;                 // min over j, per i
    int* __restrict__ bwd = mins + (BATCH + b) * NPTS;       // min over i, per j

    const int tid = threadIdx.x;
    const int i0  = blockIdx.x * PTILE + tid;
    const int j0  = blockIdx.y * CHUNK;

    // Stage target chunk into LDS + init col-min array
    for (int k = tid; k < CHUNK; k += BLOCK) {
        const float* qp = Q + 3 * (j0 + k);
        qs[0][k] = qp[0];
        qs[1][k] = qp[1];
        qs[2][k] = qp[2];
        cmin_s[k] = 0x7F7F7F7F;   // 3.39e38f
    }
    __syncthreads();

    float px[RPT], py[RPT], pz[RPT], m[RPT];
#pragma unroll
    for (int r = 0; r < RPT; ++r) {
        const float* pp = P + 3 * (i0 + r * BLOCK);
        px[r] = pp[0];
        py[r] = pp[1];
        pz[r] = pp[2];
        m[r]  = 3.0e38f;
    }

    for (int jj = 0; jj < CHUNK; ++jj) {
        const int   j  = (tid + jj) & (CHUNK - 1);   // staggered: unique per lane
        const float qx = qs[0][j];
        const float qy = qs[1][j];
        const float qz = qs[2][j];
        float d[RPT];
#pragma unroll
        for (int r = 0; r < RPT; ++r) {
            const float dx = px[r] - qx;
            const float dy = py[r] - qy;
            const float dz = pz[r] - qz;
            float t = dx * dx;
            t = fmaf(dy, dy, t);
            t = fmaf(dz, dz, t);
            d[r] = t;
            m[r] = fminf(m[r], t);
        }
        // column min over this thread's 8 rows (balanced tree), then LDS atomic
        const float c01 = fminf(d[0], d[1]);
        const float c23 = fminf(d[2], d[3]);
        const float c45 = fminf(d[4], d[5]);
        const float c67 = fminf(d[6], d[7]);
        const float cm  = fminf(fminf(c01, c23), fminf(c45, c67));
        atomicMin(&cmin_s[j], __float_as_int(cm));
    }

    // forward (row) mins -> global
#pragma unroll
    for (int r = 0; r < RPT; ++r)
        atomicMin(&fwd[i0 + r * BLOCK], __float_as_int(m[r]));

    __syncthreads();
    // backward (col) mins -> global
    for (int k = tid; k < CHUNK; k += BLOCK)
        atomicMin(&bwd[j0 + k], cmin_s[k]);
}

__global__ __launch_bounds__(1024) void chamfer_reduce(
    const int* __restrict__ mins, float* __restrict__ out)
{
    __shared__ float part[16];
    const int total = 2 * BATCH * NPTS;  // 65536

    float s = 0.0f;
    for (int k = threadIdx.x; k < total; k += 1024)
        s += __int_as_float(mins[k]);

    for (int off = 32; off > 0; off >>= 1)
        s += __shfl_down(s, off, 64);
    if ((threadIdx.x & 63) == 0)
        part[threadIdx.x >> 6] = s;
    __syncthreads();

    if (threadIdx.x < 16) {
        float v = part[threadIdx.x];
        for (int off = 8; off > 0; off >>= 1)
            v += __shfl_down(v, off, 64);
        if (threadIdx.x == 0)
            out[0] = v * (1.0f / (float)(BATCH * NPTS));  // mean over 32768 + fwd/bwd sum
    }
}

extern "C" void kernel_launch(void* const* d_in, const int* in_sizes, int n_in,
                              void* d_out, int out_size, void* d_ws, size_t ws_size,
                              hipStream_t stream)
{
    const float* pred   = (const float*)d_in[0];
    const float* target = (const float*)d_in[1];
    float* out = (float*)d_out;
    int* mins  = (int*)d_ws;  // [2][BATCH][NPTS] fp32-as-int partial mins

    hipMemsetAsync(mins, 0x7F, (size_t)(2 * BATCH * NPTS) * sizeof(int), stream);

    dim3 grid(NPTS / PTILE, NCHUNK, BATCH);
    chamfer_pairs<<<grid, BLOCK, 0, stream>>>(pred, target, mins);
    chamfer_reduce<<<1, 1024, 0, stream>>>(mins, out);
}